// Round 2
// baseline (391.097 us; speedup 1.0000x reference)
//
#include <hip/hip_runtime.h>
#include <stdint.h>

// B=8, S=4096, D_IN=512, D=256.
#define B_   8
#define S_   4096
#define DIN  512
#define D_   256

typedef __attribute__((ext_vector_type(8))) short short8;   // 8 bf16 = 4 VGPRs
typedef __attribute__((ext_vector_type(4))) float floatx4;  // MFMA C/D
typedef __attribute__((ext_vector_type(4))) short short4v;

__device__ __forceinline__ void gll16(const void* g, void* lds) {
  __builtin_amdgcn_global_load_lds(
      (const __attribute__((address_space(1))) void*)g,
      (__attribute__((address_space(3))) void*)lds, 16, 0, 0);
}
__device__ __forceinline__ short f2bf(float x) {
  union { float f; unsigned u; } c; c.f = x;
  unsigned r = (c.u + 0x7FFF + ((c.u >> 16) & 1)) >> 16;  // RNE
  return (short)r;
}
__device__ __forceinline__ float bf2f(short v) {
  union { unsigned u; float f; } c; c.u = ((unsigned)(unsigned short)v) << 16;
  return c.f;
}

// ------------------------------------------------------------- dtype detect
// If d_in holds fp32 data, reading it as bf16 yields mantissa-garbage with
// random exponents (values up to ~1e38). Genuine bf16 Wq has |v| < ~0.3.
__global__ __launch_bounds__(256) void detect_kernel(
    const unsigned short* __restrict__ w, int* __restrict__ flag) {
  const int tid = threadIdx.x;
  float m = 0.f;
#pragma unroll
  for (int j = 0; j < 16; ++j) {
    float f = bf2f((short)w[tid * 16 + j]);
    m = fmaxf(m, fabsf(f));  // fmaxf drops NaN, keeps inf
  }
#pragma unroll
  for (int d = 1; d < 64; d <<= 1) m = fmaxf(m, __shfl_xor(m, d));
  __shared__ float red[4];
  if ((tid & 63) == 0) red[tid >> 6] = m;
  __syncthreads();
  if (tid == 0) {
    float mm = fmaxf(fmaxf(red[0], red[1]), fmaxf(red[2], red[3]));
    flag[0] = (mm > 1000.0f) ? 1 : 0;
  }
}

// ------------------------------------------------------------- convert/copy
// 4 elements per thread. fp32 mode: float4 -> 4x bf16. bf16 mode: raw copy.
__global__ __launch_bounds__(256) void cvt_kernel(
    const void* __restrict__ src, short* __restrict__ dst, int n,
    const int* __restrict__ flag) {
  const int i = blockIdx.x * 256 + threadIdx.x;  // quad index
  if (i * 4 >= n) return;
  if (*flag) {
    float4 v = ((const float4*)src)[i];
    short4v o;
    o[0] = f2bf(v.x); o[1] = f2bf(v.y); o[2] = f2bf(v.z); o[3] = f2bf(v.w);
    ((short4v*)dst)[i] = o;
  } else {
    ((short4v*)dst)[i] = ((const short4v*)src)[i];
  }
}

// ---------------------------------------------------------------- W transpose
// Wt[mat][n][k] = W[k][n]; 3 x 512x256 bf16
__global__ __launch_bounds__(256) void wt_kernel(
    const short* __restrict__ Wall, short* __restrict__ Wt) {
  __shared__ short tile[32][33];
  const int mat = blockIdx.z;
  const short* W = Wall + mat * (DIN * D_);
  const int n0 = blockIdx.x * 32, k0 = blockIdx.y * 32;
  const int tx = threadIdx.x & 31, ty = threadIdx.x >> 5;
#pragma unroll
  for (int i = 0; i < 4; ++i) {
    int k = ty + i * 8;
    tile[k][tx] = W[(k0 + k) * D_ + n0 + tx];
  }
  __syncthreads();
  short* o = Wt + mat * (D_ * DIN);
#pragma unroll
  for (int i = 0; i < 4; ++i) {
    int n = ty + i * 8;
    o[(n0 + n) * DIN + k0 + tx] = tile[tx][n];
  }
}

// ---------------------------------------------------------------- QKV GEMM
__global__ __launch_bounds__(256, 2) void qkv_kernel(
    const short* __restrict__ x, const short* __restrict__ Wt,
    const short* __restrict__ bb,
    short* __restrict__ Qg, short* __restrict__ Kg, short* __restrict__ Vtg) {
  __shared__ short As[2][512 * 8];
  __shared__ short Bs[2][512 * 8];
  const int tid = threadIdx.x;
  const int lane = tid & 63, w = tid >> 6;
  const int li = lane & 15, g = lane >> 4;
  const int mb = blockIdx.x;
  const int mat = blockIdx.y >> 1, nb = blockIdx.y & 1;
  const short* Ag = x + mb * 128 * DIN;
  const short* Bt = Wt + mat * (D_ * DIN) + nb * 128 * DIN;

  auto stage = [&](int buf, int k0) {
#pragma unroll
    for (int p = 0; p < 2; ++p) {
      int c = p * 256 + tid;
      int row = c >> 2, og = (c & 3) ^ (row & 3);
      gll16(Ag + row * DIN + k0 + og * 8, &As[buf][(p * 256 + w * 64) * 8]);
    }
#pragma unroll
    for (int p = 0; p < 2; ++p) {
      int c = p * 256 + tid;
      int row = c >> 2, og = (c & 3) ^ (row & 3);
      gll16(Bt + row * DIN + k0 + og * 8, &Bs[buf][(p * 256 + w * 64) * 8]);
    }
  };

  const int msub = (w & 1) * 64, nsub = (w >> 1) * 64;
  floatx4 acc[4][4];
#pragma unroll
  for (int i = 0; i < 4; ++i)
#pragma unroll
    for (int j = 0; j < 4; ++j) acc[i][j] = floatx4{0.f, 0.f, 0.f, 0.f};

  stage(0, 0);
  __syncthreads();
  for (int kt = 0; kt < 16; ++kt) {
    if (kt < 15) stage((kt + 1) & 1, (kt + 1) * 32);
    const int buf = kt & 1;
    short8 af[4], bfr[4];
#pragma unroll
    for (int mt = 0; mt < 4; ++mt) {
      int row = msub + mt * 16 + li;
      int og = g ^ (row & 3);
      af[mt] = *(const short8*)&As[buf][(row * 4 + og) * 8];
    }
#pragma unroll
    for (int nt = 0; nt < 4; ++nt) {
      int row = nsub + nt * 16 + li;
      int og = g ^ (row & 3);
      bfr[nt] = *(const short8*)&Bs[buf][(row * 4 + og) * 8];
    }
#pragma unroll
    for (int mt = 0; mt < 4; ++mt)
#pragma unroll
      for (int nt = 0; nt < 4; ++nt)
        acc[mt][nt] = __builtin_amdgcn_mfma_f32_16x16x32_bf16(
            af[mt], bfr[nt], acc[mt][nt], 0, 0, 0);
    __syncthreads();
  }

  const short* bias = bb + mat * 256;
  if (mat < 2) {
    short* O = (mat == 0) ? Qg : Kg;
#pragma unroll
    for (int nt = 0; nt < 4; ++nt) {
      float bv_ = bf2f(bias[nb * 128 + nsub + nt * 16 + li]);
#pragma unroll
      for (int mt = 0; mt < 4; ++mt)
#pragma unroll
        for (int r = 0; r < 4; ++r) {
          int m = mb * 128 + msub + mt * 16 + g * 4 + r;
          int n = nb * 128 + nsub + nt * 16 + li;
          O[m * D_ + n] = f2bf(acc[mt][nt][r] + bv_);
        }
    }
  } else {
#pragma unroll
    for (int nt = 0; nt < 4; ++nt) {
      float bv_ = bf2f(bias[nb * 128 + nsub + nt * 16 + li]);
#pragma unroll
      for (int mt = 0; mt < 4; ++mt) {
        int m0 = mb * 128 + msub + mt * 16 + g * 4;
        int batch = m0 >> 12, s = m0 & (S_ - 1);
        int n = nb * 128 + nsub + nt * 16 + li;
        short4v pk;
#pragma unroll
        for (int r = 0; r < 4; ++r) pk[r] = f2bf(acc[mt][nt][r] + bv_);
        *(short4v*)&Vtg[(batch * D_ + n) * S_ + s] = pk;
      }
    }
  }
}

// ---------------------------------------------------------------- attention
__global__ __launch_bounds__(512, 2) void attn_kernel(
    const short* __restrict__ Qg, const short* __restrict__ Kg,
    const short* __restrict__ Vtg, void* __restrict__ outv,
    const int* __restrict__ flag) {
  __shared__ short Ks[2][2048 * 8];
  __shared__ short Vs[2][2048 * 8];
  __shared__ short Ps[8][16 * 72];
  const int tid = threadIdx.x, lane = tid & 63, w = tid >> 6;
  const int li = lane & 15, g = lane >> 4;
  const int bb = blockIdx.y, q0 = blockIdx.x * 128;
  const int qrow = q0 + w * 16;

  const short* Qb = Qg + (bb * S_ + qrow) * D_;
  const short* Kb = Kg + (size_t)bb * S_ * D_;
  const short* Vb = Vtg + (size_t)bb * D_ * S_;

  short8 qf[8];
#pragma unroll
  for (int o = 0; o < 8; ++o)
    qf[o] = *(const short8*)&Qb[li * D_ + o * 32 + g * 8];

  floatx4 oa[16];
#pragma unroll
  for (int i = 0; i < 16; ++i) oa[i] = floatx4{0.f, 0.f, 0.f, 0.f};
  float mst[4], lst[4];
#pragma unroll
  for (int r = 0; r < 4; ++r) { mst[r] = -1.0e30f; lst[r] = 0.f; }

  auto stage = [&](int t, int buf) {
    const int s0 = t * 64;
#pragma unroll
    for (int p = 0; p < 4; ++p) {
      int c = p * 512 + tid;
      int s = c >> 5, og = (c & 31) ^ (s & 31);
      gll16(&Kb[(s0 + s) * D_ + og * 8], &Ks[buf][(p * 512 + w * 64) * 8]);
    }
#pragma unroll
    for (int p = 0; p < 4; ++p) {
      int c = p * 512 + tid;
      int e = c >> 3, og = (c & 7) ^ (e & 7);
      gll16(&Vb[e * S_ + s0 + og * 8], &Vs[buf][(p * 512 + w * 64) * 8]);
    }
  };

  const float cs = 0.09016844005556f;  // (1/16) * log2(e)
  stage(0, 0);
  __syncthreads();

  for (int t = 0; t < 64; ++t) {
    if (t < 63) stage(t + 1, (t + 1) & 1);
    const int buf = t & 1;

    floatx4 sc[4];
#pragma unroll
    for (int nt = 0; nt < 4; ++nt) sc[nt] = floatx4{0.f, 0.f, 0.f, 0.f};
#pragma unroll
    for (int nt = 0; nt < 4; ++nt) {
      const int sl = nt * 16 + li;
#pragma unroll
      for (int o = 0; o < 8; ++o) {
        int od = o * 4 + g;
        int chunk = sl * 32 + (od ^ (sl & 31));
        short8 kf = *(const short8*)&Ks[buf][chunk * 8];
        sc[nt] = __builtin_amdgcn_mfma_f32_16x16x32_bf16(qf[o], kf, sc[nt], 0, 0, 0);
      }
    }

    float rm[4];
#pragma unroll
    for (int r = 0; r < 4; ++r)
      rm[r] = fmaxf(fmaxf(sc[0][r], sc[1][r]), fmaxf(sc[2][r], sc[3][r]));
#pragma unroll
    for (int d = 1; d < 16; d <<= 1)
#pragma unroll
      for (int r = 0; r < 4; ++r)
        rm[r] = fmaxf(rm[r], __shfl_xor(rm[r], d));
    float al[4];
#pragma unroll
    for (int r = 0; r < 4; ++r) {
      float mn = fmaxf(mst[r], rm[r] * cs);
      al[r] = exp2f(mst[r] - mn);
      mst[r] = mn;
      lst[r] *= al[r];
    }
    float rs[4] = {0.f, 0.f, 0.f, 0.f};
#pragma unroll
    for (int nt = 0; nt < 4; ++nt)
#pragma unroll
      for (int r = 0; r < 4; ++r) {
        float p = exp2f(sc[nt][r] * cs - mst[r]);
        rs[r] += p;
        Ps[w][(g * 4 + r) * 72 + nt * 16 + li] = f2bf(p);
      }
#pragma unroll
    for (int d = 1; d < 16; d <<= 1)
#pragma unroll
      for (int r = 0; r < 4; ++r) rs[r] += __shfl_xor(rs[r], d);
#pragma unroll
    for (int r = 0; r < 4; ++r) lst[r] += rs[r];
#pragma unroll
    for (int i = 0; i < 16; ++i)
#pragma unroll
      for (int r = 0; r < 4; ++r) oa[i][r] *= al[r];

    // ensure the Ps ds_writes retire before the ds_read_b128 below, and
    // block any compiler reordering across this point
    __asm__ __volatile__("s_waitcnt lgkmcnt(0)" ::: "memory");

#pragma unroll
    for (int kb = 0; kb < 2; ++kb) {
      short8 pf = *(const short8*)&Ps[w][li * 72 + kb * 32 + g * 8];
#pragma unroll
      for (int n2 = 0; n2 < 16; ++n2) {
        int e = n2 * 16 + li, os = kb * 4 + g;
        int chunk = e * 8 + (os ^ (e & 7));
        short8 vf = *(const short8*)&Vs[buf][chunk * 8];
        oa[n2] = __builtin_amdgcn_mfma_f32_16x16x32_bf16(pf, vf, oa[n2], 0, 0, 0);
      }
    }
    __syncthreads();
  }

  const int f32o = *flag;
#pragma unroll
  for (int r = 0; r < 4; ++r) lst[r] = 1.0f / lst[r];
  if (f32o) {
    float* out = (float*)outv;
#pragma unroll
    for (int n2 = 0; n2 < 16; ++n2)
#pragma unroll
      for (int r = 0; r < 4; ++r) {
        int row = qrow + g * 4 + r, e = n2 * 16 + li;
        out[(bb * S_ + row) * D_ + e] = oa[n2][r] * lst[r];
      }
  } else {
    short* out = (short*)outv;
#pragma unroll
    for (int n2 = 0; n2 < 16; ++n2)
#pragma unroll
      for (int r = 0; r < 4; ++r) {
        int row = qrow + g * 4 + r, e = n2 * 16 + li;
        out[(bb * S_ + row) * D_ + e] = f2bf(oa[n2][r] * lst[r]);
      }
  }
}

// ---------------------------------------------------------------- launch
extern "C" void kernel_launch(void* const* d_in, const int* in_sizes, int n_in,
                              void* d_out, int out_size, void* d_ws, size_t ws_size,
                              hipStream_t stream) {
  const void* x  = d_in[0];
  const void* Wq = d_in[1];
  const void* bq = d_in[2];
  const void* Wk = d_in[3];
  const void* bk = d_in[4];
  const void* Wv = d_in[5];
  const void* bv = d_in[6];
  char* ws = (char*)d_ws;
  // ws layout (needs ~82MB):
  int*   flag = (int*)(ws);                         // 4B
  short* bbuf = (short*)(ws + 256);                 // 3*256 bf16
  short* wcv  = (short*)(ws + 4096);                // 3*131072 bf16 (768KB)
  short* Wt   = (short*)(ws + (1u << 20));          // 768KB
  short* xb   = (short*)(ws + (2u << 20));          // 32MB
  short* Qw   = (short*)(ws + (34u << 20));         // 16MB
  short* Kw   = (short*)(ws + (50u << 20));         // 16MB
  short* Vtw  = (short*)(ws + (66u << 20));         // 16MB

  hipLaunchKernelGGL(detect_kernel, dim3(1), dim3(256), 0, stream,
                     (const unsigned short*)Wq, flag);
  // convert/copy everything to bf16 in ws
  hipLaunchKernelGGL(cvt_kernel, dim3(16384), dim3(256), 0, stream,
                     x, xb, B_ * S_ * DIN, flag);
  hipLaunchKernelGGL(cvt_kernel, dim3(128), dim3(256), 0, stream,
                     Wq, wcv + 0 * DIN * D_, DIN * D_, flag);
  hipLaunchKernelGGL(cvt_kernel, dim3(128), dim3(256), 0, stream,
                     Wk, wcv + 1 * DIN * D_, DIN * D_, flag);
  hipLaunchKernelGGL(cvt_kernel, dim3(128), dim3(256), 0, stream,
                     Wv, wcv + 2 * DIN * D_, DIN * D_, flag);
  hipLaunchKernelGGL(cvt_kernel, dim3(1), dim3(256), 0, stream,
                     bq, bbuf + 0 * D_, D_, flag);
  hipLaunchKernelGGL(cvt_kernel, dim3(1), dim3(256), 0, stream,
                     bk, bbuf + 1 * D_, D_, flag);
  hipLaunchKernelGGL(cvt_kernel, dim3(1), dim3(256), 0, stream,
                     bv, bbuf + 2 * D_, D_, flag);

  hipLaunchKernelGGL(wt_kernel, dim3(8, 16, 3), dim3(256), 0, stream, wcv, Wt);
  hipLaunchKernelGGL(qkv_kernel, dim3(256, 6), dim3(256), 0, stream,
                     xb, Wt, bbuf, Qw, Kw, Vtw);
  hipLaunchKernelGGL(attn_kernel, dim3(32, 8), dim3(512), 0, stream,
                     Qw, Kw, Vtw, d_out, flag);
}